// Round 1
// baseline (122.813 us; speedup 1.0000x reference)
//
#include <hip/hip_runtime.h>

// TMPI tiled renderer: composite 512 depth-sorted 144x144 tiles into a
// 656x656 buffer with per-pixel transmittance; return cropped 512x512x3.
//
// Constants from the reference:
constexpr int HO   = 512;
constexpr int TILE = 128;
constexpr int PAD  = 8;
constexpr int HP   = TILE + 2 * PAD;   // 144
constexpr int P    = HP * HP;          // 20736
constexpr int S    = 512;
constexpr int OUTW = 512;              // cropped output is 512x512
constexpr int OUTP = OUTW * OUTW;      // 262144 per channel

// ---------------------------------------------------------------------------
// Kernel 1: stable depth sort (rank by O(S^2) comparison) + metadata pack.
// meta[rank] = { sy, sx, sigma_base, rgb_base } where
//   sigma_base = orig*P     - (sy*HP + sx)
//   rgb_base   = orig*3*P   - (sy*HP + sx)
// so in the composite loop:  addr = base(+c*P) with base = yb*HP + xb.
// NOTE: per reference, py = sy (row offset), px = sx (col offset).
// ---------------------------------------------------------------------------
__global__ __launch_bounds__(512) void sort_planes_kernel(
    const float* __restrict__ depth,
    const int*   __restrict__ sx,
    const int*   __restrict__ sy,
    int4*        __restrict__ meta)
{
    __shared__ float sd[S];
    const int i = threadIdx.x;
    sd[i] = depth[i];
    __syncthreads();

    const float di = sd[i];
    int rank = 0;
#pragma unroll 8
    for (int j = 0; j < S; ++j) {
        const float dj = sd[j];
        // stable: ties broken by original index (matches jnp.argsort stable)
        rank += (dj < di) || (dj == di && j < i);
    }

    const int sxi = sx[i];
    const int syi = sy[i];
    const int off = syi * HP + sxi;
    meta[rank] = make_int4(syi, sxi, i * P - off, i * 3 * P - off);
}

// ---------------------------------------------------------------------------
// Kernel 2: per-pixel front-to-back composite.
// Block = 64x4 pixels (lane = x -> coalesced loads of contiguous p).
// Grid  = (512/64, 512/4) = (8, 128).
// ---------------------------------------------------------------------------
__global__ __launch_bounds__(256) void composite_kernel(
    const float* __restrict__ rgb,     // [S][3][P]
    const float* __restrict__ sigma,   // [S][P]
    const int4*  __restrict__ meta,    // [S] sorted
    float*       __restrict__ out)     // [3][512][512]
{
    __shared__ int4 smeta[S];
    {
        const int t = threadIdx.y * 64 + threadIdx.x;
        smeta[t]       = meta[t];
        smeta[t + 256] = meta[t + 256];
    }
    __syncthreads();

    const int xo = blockIdx.x * 64 + threadIdx.x;   // output col 0..511
    const int yo = blockIdx.y * 4  + threadIdx.y;   // output row 0..511
    const int xb = xo + PAD;                        // buffer col
    const int yb = yo + PAD;                        // buffer row
    const int base = yb * HP + xb;                  // folds with meta bases

    float trans = 1.0f;
    float ar = 0.0f, ag = 0.0f, ab = 0.0f;

    for (int s = 0; s < S; ++s) {
        const int4 m = smeta[s];                    // broadcast LDS read
        const unsigned yy = (unsigned)(yb - m.x);
        const unsigned xx = (unsigned)(xb - m.y);
        if (yy < (unsigned)HP && xx < (unsigned)HP) {
            const float sg = sigma[m.z + base];
            const int   pr = m.w + base;
            const float w  = sg * trans;
            ar = fmaf(rgb[pr],         w, ar);
            ag = fmaf(rgb[pr + P],     w, ag);
            ab = fmaf(rgb[pr + 2 * P], w, ab);
            trans *= (1.0f - sg);
        }
    }

    const int o = yo * OUTW + xo;
    out[o]            = ar;
    out[o + OUTP]     = ag;
    out[o + 2 * OUTP] = ab;
}

// ---------------------------------------------------------------------------
extern "C" void kernel_launch(void* const* d_in, const int* in_sizes, int n_in,
                              void* d_out, int out_size, void* d_ws, size_t ws_size,
                              hipStream_t stream)
{
    const float* tgt_rgb   = (const float*)d_in[0];  // (1,S,3,P)
    const float* tgt_sigma = (const float*)d_in[1];  // (1,S,P)
    const float* mpi_depth = (const float*)d_in[2];  // (1,S)
    const int*   sx        = (const int*)d_in[3];    // (1,S) col offsets
    const int*   sy        = (const int*)d_in[4];    // (1,S) row offsets
    float*       out       = (float*)d_out;          // (1,3,512,512)
    int4*        meta      = (int4*)d_ws;            // S * 16 bytes

    sort_planes_kernel<<<1, S, 0, stream>>>(mpi_depth, sx, sy, meta);

    dim3 block(64, 4);
    dim3 grid(OUTW / 64, OUTW / 4);
    composite_kernel<<<grid, block, 0, stream>>>(tgt_rgb, tgt_sigma, meta, out);
}

// Round 3
// 63.940 us; speedup vs baseline: 1.9208x; 1.9208x over previous
//
#include <hip/hip_runtime.h>

// TMPI tiled renderer: composite 512 depth-sorted 144x144 tiles into a
// 656x656 buffer with per-pixel transmittance; return cropped 512x512x3.
constexpr int TILE = 128;
constexpr int PAD  = 8;
constexpr int HP   = TILE + 2 * PAD;   // 144
constexpr int P    = HP * HP;          // 20736
constexpr int S    = 512;
constexpr int OUTW = 512;
constexpr int OUTP = OUTW * OUTW;
constexpr int NSEG = 8;                // depth segments == waves per block

// ---------------------------------------------------------------------------
// Kernel 1: stable depth sort (O(S^2) rank) + metadata pack.
// meta[rank] = { sy, sx, i*P (sigma base), i*3*P (rgb base) }
// ---------------------------------------------------------------------------
__global__ __launch_bounds__(512) void sort_planes_kernel(
    const float* __restrict__ depth,
    const int*   __restrict__ sx,
    const int*   __restrict__ sy,
    int4*        __restrict__ meta)
{
    __shared__ float sd[S];
    const int i = threadIdx.x;
    sd[i] = depth[i];
    __syncthreads();

    const float di = sd[i];
    int rank = 0;
#pragma unroll 8
    for (int j = 0; j < S; ++j) {
        const float dj = sd[j];
        rank += (dj < di) || (dj == di && j < i);   // stable tie-break
    }
    meta[rank] = make_int4(sy[i], sx[i], i * P, i * 3 * P);
}

// ---------------------------------------------------------------------------
// Kernel 2: one block = one 64-pixel output row; 8 waves = 8 depth segments.
//  Phase A: compact the 512 sorted planes to those covering this row
//           (ballot + cross-wave prefix; order preserved).
//  Phase B: each wave composites its depth segment, branch-free
//           (clamped addresses + cndmask weight) so loads pipeline.
//  Phase C: associative fold of the 8 (color, trans) partials in LDS.
// ---------------------------------------------------------------------------
__global__ __launch_bounds__(512) void composite_kernel(
    const float* __restrict__ rgb,     // [S][3][P]
    const float* __restrict__ sigma,   // [S][P]
    const int4*  __restrict__ meta,    // [S] depth-sorted
    float*       __restrict__ out)     // [3][512][512]
{
    __shared__ int4   list[S];
    __shared__ int    cnt[NSEG];
    __shared__ float4 part[NSEG][64];

    const int tid  = threadIdx.x;
    const int w    = tid >> 6;
    const int lane = tid & 63;
    const int X0   = blockIdx.x * 64;     // output col base
    const int Y0   = blockIdx.y;          // output row
    const int yb   = Y0 + PAD;            // buffer row

    // --- Phase A: compaction (thread t inspects plane t) ---
    const int4 m = meta[tid];
    // row covered:  sy <= yb <= sy+143 ;  x-span [X0+8, X0+71] intersects tile
    const bool cov = ((unsigned)(yb - m.x) < (unsigned)HP) &&
                     ((unsigned)(X0 + 71 - m.y) < 207u);
    const unsigned long long mask = __ballot(cov);
    const int pre = __popcll(mask & ((1ull << lane) - 1ull));
    if (lane == 0) cnt[w] = __popcll(mask);
    __syncthreads();

    int off = 0, nc = 0;
    for (int i = 0; i < NSEG; ++i) {
        const int c = cnt[i];
        off += (i < w) ? c : 0;
        nc  += c;
    }
    if (cov) list[off + pre] = m;
    __syncthreads();

    // --- Phase B: composite this wave's depth segment, branch-free ---
    const int kb = (nc * w) / NSEG;
    const int ke = (nc * (w + 1)) / NSEG;
    const int xb = X0 + PAD + lane;        // buffer col for this lane

    float trans = 1.0f, ar = 0.0f, ag = 0.0f, ab = 0.0f;
#pragma unroll 4
    for (int k = kb; k < ke; ++k) {
        const int4 e = list[k];            // broadcast LDS read
        const int yy = yb - e.x;           // 0..143 guaranteed by list
        const int xx = xb - e.y;           // may be outside [0,144)
        const bool c = (unsigned)xx < (unsigned)HP;
        const int  xc = min(max(xx, 0), HP - 1);   // v_med3 clamp
        const int  o  = yy * HP + xc;
        float sg = sigma[e.z + o];
        sg = c ? sg : 0.0f;                // cndmask, no branch
        const int   pr  = e.w + o;
        const float wgt = sg * trans;
        ar = fmaf(rgb[pr],         wgt, ar);
        ag = fmaf(rgb[pr + P],     wgt, ag);
        ab = fmaf(rgb[pr + 2 * P], wgt, ab);
        trans *= (1.0f - sg);
    }
    part[w][lane] = make_float4(ar, ag, ab, trans);
    __syncthreads();

    // --- Phase C: fold partials front-to-back; wave 0 writes output ---
    if (w == 0) {
        float cr = 0.0f, cg = 0.0f, cb = 0.0f, T = 1.0f;
        for (int i = 0; i < NSEG; ++i) {
            const float4 p = part[i][lane];
            cr = fmaf(T, p.x, cr);
            cg = fmaf(T, p.y, cg);
            cb = fmaf(T, p.z, cb);
            T *= p.w;
        }
        const int o = Y0 * OUTW + X0 + lane;
        out[o]            = cr;
        out[o + OUTP]     = cg;
        out[o + 2 * OUTP] = cb;
    }
}

// ---------------------------------------------------------------------------
extern "C" void kernel_launch(void* const* d_in, const int* in_sizes, int n_in,
                              void* d_out, int out_size, void* d_ws, size_t ws_size,
                              hipStream_t stream)
{
    const float* tgt_rgb   = (const float*)d_in[0];  // (1,S,3,P)
    const float* tgt_sigma = (const float*)d_in[1];  // (1,S,P)
    const float* mpi_depth = (const float*)d_in[2];  // (1,S)
    const int*   sx        = (const int*)d_in[3];    // (1,S) col offsets
    const int*   sy        = (const int*)d_in[4];    // (1,S) row offsets
    float*       out       = (float*)d_out;          // (1,3,512,512)
    int4*        meta      = (int4*)d_ws;            // S * 16 bytes

    sort_planes_kernel<<<1, S, 0, stream>>>(mpi_depth, sx, sy, meta);

    dim3 block(512);
    dim3 grid(OUTW / 64, OUTW);          // one block per 64-pixel output row
    composite_kernel<<<grid, block, 0, stream>>>(tgt_rgb, tgt_sigma, meta, out);
}